// Round 11
// baseline (193.397 us; speedup 1.0000x reference)
//
#include <hip/hip_runtime.h>
#include <stdint.h>

#define DMAX   80
#define BLK    256
#define XW     96      // xsel row stride (global, >= m+1)
#define EPBMAX 2048    // output elements per block (8 KB): compact write window
#define NR     2       // rows staged per block (epb <= T guarantees <=2)

typedef float f32x4 __attribute__((ext_vector_type(4)));

// ---------------------------------------------------------------------------
// Setup: mask detect + compact idx; pair16 (i|j<<8); column table with 3
// shifted copies (copy s at tab[s*tpad + (c-s)]) so any column phase has an
// aligned vector load.  Entry: u16 p|k<<10 (if P<1024 && m<63) else u32
// p|k<<16.  column c = pps[p] * xsel[k]:
//   [0,m)      order-1: p=P (sentinel pps=1), k=c
//   [m, m+P)   order-2: p=rank,               k=m (sentinel xsel=1)
//   [m+P, T)   order-3: run over k in [j,m) per pair (i,j)
// ---------------------------------------------------------------------------
__global__ void maskde_setup(const void* __restrict__ mask_raw, int m,
                             int* __restrict__ idx_out,
                             uint16_t* __restrict__ pair16,
                             uint16_t* __restrict__ tab16,
                             uint32_t* __restrict__ tab32,
                             int use16, int tpad, int T, int P) {
    int tid = blockIdx.x * blockDim.x + threadIdx.x;

    if (tid == 0) {
        const uint8_t* b8  = (const uint8_t*)mask_raw;
        const int*     b32 = (const int*)mask_raw;
        const float*   bf  = (const float*)mask_raw;
        int cnt = 0; bool ok = true;
        for (int i = 0; i < DMAX; ++i) { uint8_t v = b8[i]; if (v > 1) ok = false; cnt += (v != 0); }
        int mode;
        if (ok && cnt == m) {
            mode = 0;
        } else {
            cnt = 0; ok = true;
            for (int i = 0; i < DMAX; ++i) { int v = b32[i]; if (v != 0 && v != 1) ok = false; cnt += (v != 0); }
            mode = (ok && cnt == m) ? 1 : 2;
        }
        int k = 0;
        for (int i = 0; i < DMAX && k < m; ++i) {
            bool on = (mode == 0) ? (b8[i] != 0)
                    : (mode == 1) ? (b32[i] != 0)
                                  : (bf[i] != 0.0f);
            if (on) idx_out[k++] = i;
        }
    }

    int stride = gridDim.x * blockDim.x;
    for (int p = tid; p < P; p += stride) {
        int rem = p, i = 0;
        while (rem >= m - i) { rem -= (m - i); ++i; }
        int j = i + rem;

        pair16[p] = (uint16_t)(i | (j << 8));

        #define WR4(c, pf, kf) do {                                          \
            int _c = (c);                                                    \
            if (use16) {                                                     \
                uint16_t _v = (uint16_t)((pf) | ((kf) << 10));               \
                tab16[_c] = _v;                                              \
                if (_c >= 1) tab16[tpad     + _c - 1] = _v;                  \
                if (_c >= 2) tab16[2 * tpad + _c - 2] = _v;                  \
                if (_c >= 3) tab16[3 * tpad + _c - 3] = _v;                  \
            } else {                                                         \
                uint32_t _v = (uint32_t)(pf) | ((uint32_t)(kf) << 16);       \
                tab32[_c] = _v;                                              \
                if (_c >= 1) tab32[tpad     + _c - 1] = _v;                  \
                if (_c >= 2) tab32[2 * tpad + _c - 2] = _v;                  \
                if (_c >= 3) tab32[3 * tpad + _c - 3] = _v;                  \
            }                                                                \
        } while (0)

        if (p < m) WR4(p, P, p);                  // order-1
        WR4(m + p, p, m);                         // order-2

        int mi = m - i;
        long long Si  = ((long long)m * (m + 1) * (m + 2)
                       - (long long)mi * (mi + 1) * (mi + 2)) / 6;
        int Rij = ((m - i) + (m - j + 1)) * (j - i) / 2;
        int base = m + P + (int)Si + Rij;
        for (int k3 = j; k3 < m; ++k3)
            WR4(base + (k3 - j), p, k3);
        #undef WR4
    }
}

// ---------------------------------------------------------------------------
// xsel[row*XW + k] = x[row*80 + idx[k]] for k<m, 1.0 for k>=m (sentinel).
// ---------------------------------------------------------------------------
__global__ void maskde_xsel(const float* __restrict__ x,
                            const int* __restrict__ idx,
                            float* __restrict__ xsel, int m, int rows) {
    int g = blockIdx.x * BLK + threadIdx.x;
    int total = rows * XW;
    for (; g < total; g += gridDim.x * BLK) {
        int row = g / XW, k = g - row * XW;
        xsel[g] = (k < m) ? x[row * DMAX + idx[k]] : 1.0f;
    }
}

// ---------------------------------------------------------------------------
// ppsall[row*PPW + p] = xsel_i * xsel_j (p<P); 1.0 for p in [P, PPW)
// (sentinel + pad).  Coalesced row-major (~31 MB).
// ---------------------------------------------------------------------------
__global__ void maskde_ppsall(const float* __restrict__ xsel,
                              const uint16_t* __restrict__ pair16,
                              float* __restrict__ ppsall, int P, int PPW) {
    int p   = blockIdx.x * BLK + threadIdx.x;
    int row = blockIdx.y;
    if (p >= PPW) return;
    float v = 1.0f;
    if (p < P) {
        uint32_t ij = pair16[p];
        const float* xr = xsel + row * XW;
        v = xr[ij & 0xFF] * xr[(ij >> 8) & 0xFF];
    }
    ppsall[(size_t)row * PPW + p] = v;
}

// ---------------------------------------------------------------------------
// Expand: block b writes flat [b*epb, (b+1)*epb) (consecutive blocks =
// consecutive bytes; small epb keeps the device-wide in-flight write window
// compact => DRAM-page friendly, fill-like).  Prologue is gather-free:
// sequential uint4 L2->LDS copies of <=2 rows' pps + xsel stage.  Hot loop:
// 1 aligned uint2/uint4 table load + 8 LDS reads + 4 muls + 1 aligned
// float4 store.
// ---------------------------------------------------------------------------
template<bool U16>
__global__ __launch_bounds__(BLK) void
maskde_expand(const float* __restrict__ xsel,
              const float* __restrict__ ppsall,
              const uint16_t* __restrict__ tab16,
              const uint32_t* __restrict__ tab32,
              int tpad, float* __restrict__ out,
              int T, int PPW, int rows, int epb, int total) {
    constexpr int XLT = U16 ? 64 : XW;    // xls row stride (k < m+1)
    extern __shared__ float sm[];
    float* xls = sm;               // NR * XLT
    float* pps = sm + NR * XLT;    // NR * PPW

    const int tid = threadIdx.x;
    const int e0  = blockIdx.x * epb;
    if (e0 >= total) return;
    const int eend = (e0 + epb < total) ? e0 + epb : total;
    const int r0 = e0 / T;

    // stage xls (sentinels already in xsel)
    for (int q = tid; q < NR * XLT; q += BLK) {
        int rr = q / XLT, k = q - rr * XLT;
        int row = r0 + rr;
        xls[q] = (row < rows) ? xsel[row * XW + k] : 1.0f;
    }
    // stage pps rows: sequential uint4 copies (L2-hot)
    const int nu4 = PPW >> 2;
    for (int q = tid; q < NR * nu4; q += BLK) {
        int rr = q / nu4, u = q - rr * nu4;
        int row = r0 + rr;
        if (row < rows)
            *(f32x4*)(pps + rr * PPW + 4 * u) =
                *(const f32x4*)(ppsall + (size_t)row * PPW + 4 * u);
    }
    __syncthreads();

    // row segments (<= NR)
    int a = e0;
    for (int rr = 0; rr < NR && a < eend; ++rr) {
        const int row = r0 + rr;
        const long long rowend = (long long)(row + 1) * T;
        const int b = (int)(rowend < (long long)eend ? rowend : (long long)eend);
        const float* xr = xls + rr * XLT;
        const float* pr = pps + rr * PPW;
        const int cbase = a - row * T;

        int ahead = a + ((4 - (a & 3)) & 3);
        if (ahead > b) ahead = b;

        // scalar head (<=3 elems, base table copy)
        if (tid < ahead - a) {
            int c = cbase + tid;
            uint32_t p_, k_;
            if constexpr (U16) { uint16_t t = tab16[c]; p_ = t & 0x3FF; k_ = t >> 10; }
            else               { uint32_t t = tab32[c]; p_ = t & 0xFFFF; k_ = t >> 16; }
            out[a + tid] = pr[p_] * xr[k_];
        }

        const int nq    = (b - ahead) >> 2;
        const int calig = cbase + (ahead - a);
        const int s4    = calig & 3;

        if constexpr (U16) {
            const uint16_t* tb = tab16 + (size_t)s4 * tpad + (calig - s4);
            for (int q = tid; q < nq; q += BLK) {
                uint2 t = *(const uint2*)(tb + 4 * q);   // 8B aligned
                f32x4 o;
                o.x = pr[t.x & 0x3FF]         * xr[(t.x >> 10) & 0x3F];
                o.y = pr[(t.x >> 16) & 0x3FF] * xr[t.x >> 26];
                o.z = pr[t.y & 0x3FF]         * xr[(t.y >> 10) & 0x3F];
                o.w = pr[(t.y >> 16) & 0x3FF] * xr[t.y >> 26];
                *(f32x4*)(out + ahead + 4 * q) = o;      // 16B aligned
            }
        } else {
            const uint32_t* tb = tab32 + (size_t)s4 * tpad + (calig - s4);
            for (int q = tid; q < nq; q += BLK) {
                uint4 t = *(const uint4*)(tb + 4 * q);   // 16B aligned
                f32x4 o;
                o.x = pr[t.x & 0xFFFF] * xr[t.x >> 16];
                o.y = pr[t.y & 0xFFFF] * xr[t.y >> 16];
                o.z = pr[t.z & 0xFFFF] * xr[t.z >> 16];
                o.w = pr[t.w & 0xFFFF] * xr[t.w >> 16];
                *(f32x4*)(out + ahead + 4 * q) = o;
            }
        }

        // scalar tail (<=3 elems, base table copy)
        const int ts = ahead + 4 * nq;
        if (tid < b - ts) {
            int c = cbase + (ts - a) + tid;
            uint32_t p_, k_;
            if constexpr (U16) { uint16_t t = tab16[c]; p_ = t & 0x3FF; k_ = t >> 10; }
            else               { uint32_t t = tab32[c]; p_ = t & 0xFFFF; k_ = t >> 16; }
            out[ts + tid] = pr[p_] * xr[k_];
        }
        a = b;
    }
}

extern "C" void kernel_launch(void* const* d_in, const int* in_sizes, int n_in,
                              void* d_out, int out_size, void* d_ws, size_t ws_size,
                              hipStream_t stream) {
    const float* x    = (const float*)d_in[0];
    const void*  mask = d_in[1];
    float*       out  = (float*)d_out;

    int rows = in_sizes[0] / DMAX;
    if (rows <= 0 || out_size <= 0) return;
    long long Tll = (long long)out_size / rows;

    // recover m from T(m) = m + m(m+1)/2 + m(m+1)(m+2)/6
    int m = -1;
    for (int mm = 0; mm <= DMAX; ++mm) {
        long long t = (long long)mm
                    + (long long)mm * (mm + 1) / 2
                    + (long long)mm * (mm + 1) * (mm + 2) / 6;
        if (t == Tll) { m = mm; break; }
    }
    if (m <= 0) return;

    int T     = (int)Tll;
    int P     = m * (m + 1) / 2;
    int PPW   = (P + 1 + 3) & ~3;          // pps row stride (16B mult)
    int tpad  = (T + 3) & ~3;
    int total = rows * T;
    int use16 = (P < 1024 && m < 63) ? 1 : 0;

    int epb = EPBMAX;
    if (epb > T) epb = T & ~3;             // guarantee <= NR rows per block
    if (epb < 4) epb = 4;

    // workspace layout (256B-aligned regions)
    char* ws = (char*)d_ws;
    int*      idx    = (int*)ws;                              // 512 B
    uint16_t* pair16 = (uint16_t*)(ws + 1024);                // 2P B
    uint16_t* tab16  = (uint16_t*)(ws + 32768);               // 4*tpad u16
    uint32_t* tab32  = (uint32_t*)(ws + 32768);               // 4*tpad u32 (aliased)
    size_t off_xsel  = 32768 + (size_t)4 * tpad * 4 + 256;
    off_xsel = (off_xsel + 255) & ~(size_t)255;
    float*    xsel   = (float*)(ws + off_xsel);               // rows*XW f32
    size_t off_pps   = off_xsel + (size_t)rows * XW * 4;
    off_pps = (off_pps + 255) & ~(size_t)255;
    float*    ppsall = (float*)(ws + off_pps);                // rows*PPW f32

    int sblocks = (P + 255) / 256;
    if (sblocks < 1) sblocks = 1;
    maskde_setup<<<sblocks, 256, 0, stream>>>(mask, m, idx, pair16, tab16,
                                              tab32, use16, tpad, T, P);

    int xblocks = (rows * XW + BLK - 1) / BLK;
    if (xblocks > 2048) xblocks = 2048;
    maskde_xsel<<<xblocks, BLK, 0, stream>>>(x, idx, xsel, m, rows);

    dim3 pgrid((PPW + BLK - 1) / BLK, rows);
    maskde_ppsall<<<pgrid, BLK, 0, stream>>>(xsel, pair16, ppsall, P, PPW);

    int nb = (total + epb - 1) / epb;
    size_t shmem = (size_t)(NR * XW + NR * PPW) * sizeof(float);
    if (use16)
        maskde_expand<true><<<nb, BLK, shmem, stream>>>(xsel, ppsall, tab16,
                                                        tab32, tpad, out, T,
                                                        PPW, rows, epb, total);
    else
        maskde_expand<false><<<nb, BLK, shmem, stream>>>(xsel, ppsall, tab16,
                                                         tab32, tpad, out, T,
                                                         PPW, rows, epb, total);
}

// Round 12
// 161.125 us; speedup vs baseline: 1.2003x; 1.2003x over previous
//
#include <hip/hip_runtime.h>
#include <stdint.h>

#define DMAX 80
#define BLK  256
#define XW   96      // xsel row stride (>= m+1)
#define EPB  2048    // output elements per block (8 KB): compact write window

typedef float f32x4 __attribute__((ext_vector_type(4)));

// ---------------------------------------------------------------------------
// Setup: mask detect + compact idx; pair16 (i|j<<8); coltab base copy plus 3
// shifted copies (copy s at coltab[s*tpad + (c-s)]) so a 16B-aligned uint4
// load exists for any column phase.
//   column c = pps[p] * xsel[k]; entry = p | k<<16
//     [0,m)      order-1: p=P (sentinel pps=1), k=c
//     [m, m+P)   order-2: p=rank,               k=m (sentinel x=1)
//     [m+P, T)   order-3: run over k in [j,m) per pair (i,j)
// ---------------------------------------------------------------------------
__global__ void maskde_setup(const void* __restrict__ mask_raw, int m,
                             int* __restrict__ idx_out,
                             uint16_t* __restrict__ pair16,
                             uint32_t* __restrict__ coltab,
                             int tpad, int T, int P) {
    int tid = blockIdx.x * blockDim.x + threadIdx.x;

    if (tid == 0) {
        const uint8_t* b8  = (const uint8_t*)mask_raw;
        const int*     b32 = (const int*)mask_raw;
        const float*   bf  = (const float*)mask_raw;
        int cnt = 0; bool ok = true;
        for (int i = 0; i < DMAX; ++i) { uint8_t v = b8[i]; if (v > 1) ok = false; cnt += (v != 0); }
        int mode;
        if (ok && cnt == m) {
            mode = 0;
        } else {
            cnt = 0; ok = true;
            for (int i = 0; i < DMAX; ++i) { int v = b32[i]; if (v != 0 && v != 1) ok = false; cnt += (v != 0); }
            mode = (ok && cnt == m) ? 1 : 2;
        }
        int k = 0;
        for (int i = 0; i < DMAX && k < m; ++i) {
            bool on = (mode == 0) ? (b8[i] != 0)
                    : (mode == 1) ? (b32[i] != 0)
                                  : (bf[i] != 0.0f);
            if (on) idx_out[k++] = i;
        }
    }

    int stride = gridDim.x * blockDim.x;
    for (int p = tid; p < P; p += stride) {
        int rem = p, i = 0;
        while (rem >= m - i) { rem -= (m - i); ++i; }
        int j = i + rem;

        pair16[p] = (uint16_t)(i | (j << 8));

        #define WR4(c, v) do {                                              \
            int _c = (c); uint32_t _v = (v);                                \
            coltab[_c] = _v;                                                \
            if (_c >= 1) coltab[tpad     + _c - 1] = _v;                    \
            if (_c >= 2) coltab[2 * tpad + _c - 2] = _v;                    \
            if (_c >= 3) coltab[3 * tpad + _c - 3] = _v;                    \
        } while (0)

        if (p < m)
            WR4(p, (uint32_t)P | ((uint32_t)p << 16));        // order-1
        WR4(m + p, (uint32_t)p | ((uint32_t)m << 16));        // order-2

        int mi = m - i;
        long long Si  = ((long long)m * (m + 1) * (m + 2)
                       - (long long)mi * (mi + 1) * (mi + 2)) / 6;
        int Rij = ((m - i) + (m - j + 1)) * (j - i) / 2;
        int base = m + P + (int)Si + Rij;
        for (int k3 = j; k3 < m; ++k3)
            WR4(base + (k3 - j), (uint32_t)p | ((uint32_t)k3 << 16));
        #undef WR4
    }
}

// ---------------------------------------------------------------------------
// xsel[row*XW + k] = x[row*80 + idx[k]] for k<m, 1.0 for k>=m (sentinel).
// ---------------------------------------------------------------------------
__global__ void maskde_xsel(const float* __restrict__ x,
                            const int* __restrict__ idx,
                            float* __restrict__ xsel, int m, int rows) {
    int g = blockIdx.x * BLK + threadIdx.x;
    int total = rows * XW;
    for (; g < total; g += gridDim.x * BLK) {
        int row = g / XW, k = g - row * XW;
        xsel[g] = (k < m) ? x[row * DMAX + idx[k]] : 1.0f;
    }
}

// ---------------------------------------------------------------------------
// Expand, fill-shaped (v8 structure, EPB=2048): block b writes flat
// [b*EPB,(b+1)*EPB) -- consecutive blocks = consecutive bytes, compact
// 16 MB device-wide write window.  Spans <=2 rows; second row staged and
// pair-multiplied ONLY if the span crosses the row boundary (lazy).
// Hot loop: 1 aligned uint4 table load (L2) + 8 LDS reads + 4 muls +
// 1 aligned float4 store, 2 iterations per thread.
// ---------------------------------------------------------------------------
__global__ __launch_bounds__(BLK) void
maskde_expand(const float* __restrict__ xsel,
              const uint16_t* __restrict__ pair16,
              const uint32_t* __restrict__ coltab, int tpad,
              float* __restrict__ out, int m, int T, int P,
              int rows, int total) {
    extern __shared__ float sm[];
    float* xls0 = sm;            // XW
    float* xls1 = sm + XW;       // XW
    float* pps0 = sm + 2 * XW;   // P+1
    float* pps1 = pps0 + (P + 1);

    const int tid  = threadIdx.x;
    const int e0   = blockIdx.x * EPB;
    const int eend = (e0 + EPB < total) ? e0 + EPB : total;
    const int r0   = e0 / T;
    const int r0start = r0 * T;
    const bool need1 = ((eend - 1) / T) > r0;   // span crosses into row r0+1

    // gather selected values (waves 0-1: row0, waves 2-3: row1 if needed)
    if (tid < XW) {
        xls0[tid] = xsel[r0 * XW + tid];
    } else if (tid >= 128 && tid < 128 + XW) {
        int k = tid - 128;
        xls1[k] = need1 ? xsel[(r0 + 1) * XW + k] : 1.0f;
    }
    __syncthreads();

    // pair products (+ sentinel at P); second row only if needed
    for (int p = tid; p <= P; p += BLK) {
        float v0 = 1.0f, v1 = 1.0f;
        if (p < P) {
            uint32_t ij = pair16[p];
            int i = ij & 0xFF, j = (ij >> 8) & 0xFF;
            v0 = xls0[i] * xls0[j];
            if (need1) v1 = xls1[i] * xls1[j];
        }
        pps0[p] = v0;
        if (need1) pps1[p] = v1;
    }
    __syncthreads();

#pragma unroll
    for (int it = 0; it < EPB / (4 * BLK); ++it) {
        int ee = e0 + (tid << 2) + it * (4 * BLK);
        if (ee >= total) break;
        int c = ee - r0start;
        const float* pS = pps0;
        const float* xS = xls0;
        if (c >= T) { c -= T; pS = pps1; xS = xls1; }

        if (c <= T - 4 && ee + 3 < total) {
            int s = c & 3;
            uint4 t = *(const uint4*)(coltab + (size_t)s * tpad + (c - s));
            f32x4 o;
            o.x = pS[t.x & 0xFFFF] * xS[t.x >> 16];
            o.y = pS[t.y & 0xFFFF] * xS[t.y >> 16];
            o.z = pS[t.z & 0xFFFF] * xS[t.z >> 16];
            o.w = pS[t.w & 0xFFFF] * xS[t.w >> 16];
            *(f32x4*)(out + ee) = o;   // ee % 4 == 0 -> 16B aligned
        } else {
            // row-crossing quad or buffer tail: scalar
            for (int u = 0; u < 4; ++u) {
                int e2 = ee + u;
                if (e2 >= total) break;
                int c2 = e2 - r0start;
                const float* p2 = pps0;
                const float* x2 = xls0;
                if (c2 >= T) { c2 -= T; p2 = pps1; x2 = xls1; }
                uint32_t en = coltab[c2];
                out[e2] = p2[en & 0xFFFF] * x2[en >> 16];
            }
        }
    }
}

extern "C" void kernel_launch(void* const* d_in, const int* in_sizes, int n_in,
                              void* d_out, int out_size, void* d_ws, size_t ws_size,
                              hipStream_t stream) {
    const float* x    = (const float*)d_in[0];
    const void*  mask = d_in[1];
    float*       out  = (float*)d_out;

    int rows = in_sizes[0] / DMAX;
    if (rows <= 0 || out_size <= 0) return;
    long long Tll = (long long)out_size / rows;

    // recover m from T(m) = m + m(m+1)/2 + m(m+1)(m+2)/6
    int m = -1;
    for (int mm = 0; mm <= DMAX; ++mm) {
        long long t = (long long)mm
                    + (long long)mm * (mm + 1) / 2
                    + (long long)mm * (mm + 1) * (mm + 2) / 6;
        if (t == Tll) { m = mm; break; }
    }
    if (m <= 0) return;

    int T     = (int)Tll;
    int P     = m * (m + 1) / 2;
    int tpad  = (T + 3) & ~3;
    int total = rows * T;

    // workspace layout (256B-aligned regions)
    char* ws = (char*)d_ws;
    int*      idx    = (int*)ws;                              // 512 B
    uint16_t* pair16 = (uint16_t*)(ws + 1024);                // 2P B
    uint32_t* coltab = (uint32_t*)(ws + 32768);               // 4*tpad u32
    size_t off_xsel  = 32768 + (size_t)4 * tpad * 4 + 256;
    off_xsel = (off_xsel + 255) & ~(size_t)255;
    float*    xsel   = (float*)(ws + off_xsel);               // rows*XW f32

    int sblocks = (P + 255) / 256;
    if (sblocks < 1) sblocks = 1;
    maskde_setup<<<sblocks, 256, 0, stream>>>(mask, m, idx, pair16, coltab,
                                              tpad, T, P);

    int xblocks = (rows * XW + BLK - 1) / BLK;
    if (xblocks > 2048) xblocks = 2048;
    maskde_xsel<<<xblocks, BLK, 0, stream>>>(x, idx, xsel, m, rows);

    int nb = (total + EPB - 1) / EPB;
    size_t shmem = (size_t)(2 * XW + 2 * (P + 1)) * sizeof(float);
    maskde_expand<<<nb, BLK, shmem, stream>>>(xsel, pair16, coltab, tpad,
                                              out, m, T, P, rows, total);
}

// Round 13
// 123.671 us; speedup vs baseline: 1.5638x; 1.3029x over previous
//
#include <hip/hip_runtime.h>
#include <stdint.h>

#define DMAX 80
#define BLK  256
#define XW   96      // xsel row stride (>= m+1, sentinel 1.0 at k>=m)
#define EPB  2048    // output elements per block (8 KB): compact write window

typedef float f32x4 __attribute__((ext_vector_type(4)));

// ---------------------------------------------------------------------------
// Setup: mask detect + compact idx; coltab of 3-index entries i|j<<8|k<<16
// (column c = xsel[i]*xsel[j]*xsel[k], sentinel index m -> 1.0), plus 3
// shifted copies (copy s at coltab[s*tpad + (c-s)] holds column c) so any
// column phase s = c&3 has a 16B-aligned uint4 load.
//   [0,m)      order-1: (c, m, m)
//   [m, m+P)   order-2: (i, j, m)
//   [m+P, T)   order-3: (i, j, k), k in [j,m) per pair (i,j)
// ---------------------------------------------------------------------------
__global__ void maskde_setup(const void* __restrict__ mask_raw, int m,
                             int* __restrict__ idx_out,
                             uint32_t* __restrict__ coltab,
                             int tpad, int T, int P) {
    int tid = blockIdx.x * blockDim.x + threadIdx.x;

    if (tid == 0) {
        const uint8_t* b8  = (const uint8_t*)mask_raw;
        const int*     b32 = (const int*)mask_raw;
        const float*   bf  = (const float*)mask_raw;
        int cnt = 0; bool ok = true;
        for (int i = 0; i < DMAX; ++i) { uint8_t v = b8[i]; if (v > 1) ok = false; cnt += (v != 0); }
        int mode;
        if (ok && cnt == m) {
            mode = 0;
        } else {
            cnt = 0; ok = true;
            for (int i = 0; i < DMAX; ++i) { int v = b32[i]; if (v != 0 && v != 1) ok = false; cnt += (v != 0); }
            mode = (ok && cnt == m) ? 1 : 2;
        }
        int k = 0;
        for (int i = 0; i < DMAX && k < m; ++i) {
            bool on = (mode == 0) ? (b8[i] != 0)
                    : (mode == 1) ? (b32[i] != 0)
                                  : (bf[i] != 0.0f);
            if (on) idx_out[k++] = i;
        }
    }

    int stride = gridDim.x * blockDim.x;
    for (int p = tid; p < P; p += stride) {
        int rem = p, i = 0;
        while (rem >= m - i) { rem -= (m - i); ++i; }
        int j = i + rem;

        #define WR4(c, v) do {                                              \
            int _c = (c); uint32_t _v = (v);                                \
            coltab[_c] = _v;                                                \
            if (_c >= 1) coltab[tpad     + _c - 1] = _v;                    \
            if (_c >= 2) coltab[2 * tpad + _c - 2] = _v;                    \
            if (_c >= 3) coltab[3 * tpad + _c - 3] = _v;                    \
        } while (0)

        uint32_t mm8  = (uint32_t)m << 8;
        uint32_t mm16 = (uint32_t)m << 16;
        if (p < m)
            WR4(p, (uint32_t)p | mm8 | mm16);                       // order-1
        WR4(m + p, (uint32_t)i | ((uint32_t)j << 8) | mm16);        // order-2

        int mi = m - i;
        long long Si  = ((long long)m * (m + 1) * (m + 2)
                       - (long long)mi * (mi + 1) * (mi + 2)) / 6;
        int Rij = ((m - i) + (m - j + 1)) * (j - i) / 2;
        int base = m + P + (int)Si + Rij;
        uint32_t ij = (uint32_t)i | ((uint32_t)j << 8);
        for (int k3 = j; k3 < m; ++k3)
            WR4(base + (k3 - j), ij | ((uint32_t)k3 << 16));
        #undef WR4
    }
}

// ---------------------------------------------------------------------------
// xsel[row*XW + k] = x[row*80 + idx[k]] for k<m, 1.0 for k>=m (sentinel).
// ---------------------------------------------------------------------------
__global__ void maskde_xsel(const float* __restrict__ x,
                            const int* __restrict__ idx,
                            float* __restrict__ xsel, int m, int rows) {
    int g = blockIdx.x * BLK + threadIdx.x;
    int total = rows * XW;
    for (; g < total; g += gridDim.x * BLK) {
        int row = g / XW, k = g - row * XW;
        xsel[g] = (k < m) ? x[row * DMAX + idx[k]] : 1.0f;
    }
}

// ---------------------------------------------------------------------------
// Expand, fill-shaped, prologue-free: block b writes flat [b*EPB,(b+1)*EPB)
// (consecutive blocks = consecutive bytes; 16 MB device-wide write window).
// Prologue = 2x96-float xls gather + ONE barrier (no pps build).  Hot loop:
// 1 aligned uint4 table load (L2) + 12 LDS reads + 8 muls + 1 aligned
// float4 store, 2 iterations per thread.
// ---------------------------------------------------------------------------
__global__ __launch_bounds__(BLK) void
maskde_expand(const float* __restrict__ xsel,
              const uint32_t* __restrict__ coltab, int tpad,
              float* __restrict__ out, int T, int rows, int total) {
    __shared__ float xls0[XW];
    __shared__ float xls1[XW];

    const int tid  = threadIdx.x;
    const int e0   = blockIdx.x * EPB;
    if (e0 >= total) return;
    const int eend = (e0 + EPB < total) ? e0 + EPB : total;
    const int r0   = e0 / T;
    const int r0start = r0 * T;
    const bool need1 = ((eend - 1) / T) > r0;   // span crosses into row r0+1

    // prologue: gather selected values (lazy for second row)
    if (tid < XW) {
        xls0[tid] = xsel[r0 * XW + tid];
    } else if (tid >= 128 && tid < 128 + XW) {
        int k = tid - 128;
        xls1[k] = need1 ? xsel[(r0 + 1) * XW + k] : 1.0f;
    }
    __syncthreads();

#pragma unroll
    for (int it = 0; it < EPB / (4 * BLK); ++it) {
        int ee = e0 + (tid << 2) + it * (4 * BLK);
        if (ee >= total) break;
        int c = ee - r0start;
        const float* xS = xls0;
        if (c >= T) { c -= T; xS = xls1; }

        if (c <= T - 4 && ee + 3 < total) {
            int s = c & 3;
            uint4 t = *(const uint4*)(coltab + (size_t)s * tpad + (c - s));
            f32x4 o;
            o.x = xS[t.x & 0xFF] * xS[(t.x >> 8) & 0xFF] * xS[t.x >> 16];
            o.y = xS[t.y & 0xFF] * xS[(t.y >> 8) & 0xFF] * xS[t.y >> 16];
            o.z = xS[t.z & 0xFF] * xS[(t.z >> 8) & 0xFF] * xS[t.z >> 16];
            o.w = xS[t.w & 0xFF] * xS[(t.w >> 8) & 0xFF] * xS[t.w >> 16];
            *(f32x4*)(out + ee) = o;   // ee % 4 == 0 -> 16B aligned
        } else {
            // row-crossing quad or buffer tail: scalar (base table copy)
            for (int u = 0; u < 4; ++u) {
                int e2 = ee + u;
                if (e2 >= total) break;
                int c2 = e2 - r0start;
                const float* x2 = xls0;
                if (c2 >= T) { c2 -= T; x2 = xls1; }
                uint32_t en = coltab[c2];
                out[e2] = x2[en & 0xFF] * x2[(en >> 8) & 0xFF] * x2[en >> 16];
            }
        }
    }
}

extern "C" void kernel_launch(void* const* d_in, const int* in_sizes, int n_in,
                              void* d_out, int out_size, void* d_ws, size_t ws_size,
                              hipStream_t stream) {
    const float* x    = (const float*)d_in[0];
    const void*  mask = d_in[1];
    float*       out  = (float*)d_out;

    int rows = in_sizes[0] / DMAX;
    if (rows <= 0 || out_size <= 0) return;
    long long Tll = (long long)out_size / rows;

    // recover m from T(m) = m + m(m+1)/2 + m(m+1)(m+2)/6
    int m = -1;
    for (int mm = 0; mm <= DMAX; ++mm) {
        long long t = (long long)mm
                    + (long long)mm * (mm + 1) / 2
                    + (long long)mm * (mm + 1) * (mm + 2) / 6;
        if (t == Tll) { m = mm; break; }
    }
    if (m <= 0) return;

    int T     = (int)Tll;
    int P     = m * (m + 1) / 2;
    int tpad  = (T + 3) & ~3;
    int total = rows * T;

    // workspace layout (256B-aligned regions)
    char* ws = (char*)d_ws;
    int*      idx    = (int*)ws;                              // 512 B
    uint32_t* coltab = (uint32_t*)(ws + 32768);               // 4*tpad u32
    size_t off_xsel  = 32768 + (size_t)4 * tpad * 4 + 256;
    off_xsel = (off_xsel + 255) & ~(size_t)255;
    float*    xsel   = (float*)(ws + off_xsel);               // rows*XW f32

    int sblocks = (P + 255) / 256;
    if (sblocks < 1) sblocks = 1;
    maskde_setup<<<sblocks, 256, 0, stream>>>(mask, m, idx, coltab,
                                              tpad, T, P);

    int xblocks = (rows * XW + BLK - 1) / BLK;
    if (xblocks > 2048) xblocks = 2048;
    maskde_xsel<<<xblocks, BLK, 0, stream>>>(x, idx, xsel, m, rows);

    int nb = (total + EPB - 1) / EPB;
    maskde_expand<<<nb, BLK, 0, stream>>>(xsel, coltab, tpad,
                                          out, T, rows, total);
}